// Round 1
// baseline (667.091 us; speedup 1.0000x reference)
//
#include <hip/hip_runtime.h>
#include <hip/hip_bf16.h>
#include <stdint.h>

#define N_NODES   65536
#define N_GRAPHS  1024
#define N_EDGES   1048576
#define IN_FEATS  512
#define HIDDEN    1024
#define H4        256
#define EMB_DIM   512
#define RDIM      1792   // 512 + 1024 + 256
#define EPS_F     1e-5f
#define SLOPE_F   0.01f

typedef __bf16 bf16;
typedef __bf16 bf16x8 __attribute__((ext_vector_type(8)));
typedef float  floatx4 __attribute__((ext_vector_type(4)));

// async global->LDS, 16B per lane. LDS dest = wave-uniform base + lane*16.
#define GLDS16(gp, lp) __builtin_amdgcn_global_load_lds( \
    (const __attribute__((address_space(1))) void*)(gp), \
    (__attribute__((address_space(3))) void*)(lp), 16, 0, 0)

// ---------------------------------------------------------------- edge pass
__global__ __launch_bounds__(256) void k_edges(
    const int* __restrict__ src, const int* __restrict__ dst,
    const float* __restrict__ ew,
    float* __restrict__ adj, float* __restrict__ deg_o, float* __restrict__ deg_i)
{
    int e = blockIdx.x * 256 + threadIdx.x;
    int s = src[e], d = dst[e];
    float w = ew[e];
    int g = s >> 6;                      // graph id (nodes are g*64..g*64+63)
    atomicAdd(&adj[((size_t)g << 12) + ((size_t)(d & 63) << 6) + (s & 63)], w);
    atomicAdd(&deg_o[s], 1.0f);
    atomicAdd(&deg_i[d], 1.0f);
}

__global__ __launch_bounds__(256) void k_scales(
    const float* __restrict__ deg_o, const float* __restrict__ deg_i,
    float* __restrict__ so, float* __restrict__ si)
{
    int n = blockIdx.x * 256 + threadIdx.x;
    so[n] = rsqrtf(fmaxf(deg_o[n], 1.0f));
    si[n] = rsqrtf(fmaxf(deg_i[n], 1.0f));
}

// adjb[g][d][s] = bf16( adj * rsqrt(deg_in[g*64+d]) )  (fold in-norm into adj rows)
__global__ __launch_bounds__(256) void k_adjconv(
    const float* __restrict__ adj, const float* __restrict__ si,
    bf16* __restrict__ adjb)
{
    int idx = blockIdx.x * 256 + threadIdx.x;   // 1024*4096
    int node = idx >> 6;                        // g*64 + d
    adjb[idx] = (bf16)(adj[idx] * si[node]);
}

// xs1 = bf16(x * rsqrt(deg_out)), r0 = per-graph mean of x  -> Rb cols [0,512)
__global__ __launch_bounds__(256) void k_prep(
    const float* __restrict__ x, const float* __restrict__ so,
    bf16* __restrict__ xs1, bf16* __restrict__ Rb)
{
    int g = blockIdx.x, t = threadIdx.x;
    __shared__ float sc[64];
    if (t < 64) sc[t] = so[g * 64 + t];
    __syncthreads();
    float s0 = 0.f, s1 = 0.f;
    for (int r = 0; r < 64; ++r) {
        size_t base = (size_t)(g * 64 + r) * IN_FEATS;
        float x0 = x[base + t], x1 = x[base + 256 + t];
        s0 += x0; s1 += x1;
        float v = sc[r];
        xs1[base + t]       = (bf16)(x0 * v);
        xs1[base + 256 + t] = (bf16)(x1 * v);
    }
    Rb[(size_t)g * RDIM + t]       = (bf16)(s0 * (1.f / 64.f));
    Rb[(size_t)g * RDIM + 256 + t] = (bf16)(s1 * (1.f / 64.f));
}

// W[K][N] -> WT[N][K] bf16 (N is a power of two)
__global__ __launch_bounds__(256) void k_transpose(
    const float* __restrict__ W, bf16* __restrict__ WT, int K, int logN)
{
    int idx = blockIdx.x * 256 + threadIdx.x;
    if (idx >= (K << logN)) return;
    int n = idx & ((1 << logN) - 1);
    int k = idx >> logN;
    WT[(size_t)n * K + k] = (bf16)W[idx];
}

// --------------------------------------------------- m97-style bf16 MFMA GEMM
// C[M,N] = A[M,K] @ BT[N,K]^T ; 128x128 tile, BK=64, 256 thr (4 waves, 2x2).
// LDS layout: 16B "units"; chunk c of row r stored at unit r*8 + (c ^ (r&7))
// so global_load_lds (dest = base + lane*16) + ds_read_b128 are conflict-free.
template<bool OUT_BF16>
__global__ __launch_bounds__(256) void k_gemm(
    const bf16* __restrict__ A, const bf16* __restrict__ BT,
    void* __restrict__ Cv, int K, int N)
{
    __shared__ __align__(16) bf16 sA[128 * 64];
    __shared__ __align__(16) bf16 sB[128 * 64];
    const int tid = threadIdx.x;
    const int lane = tid & 63, wave = tid >> 6;
    const int wm = wave & 1, wn = wave >> 1;
    const int row0 = blockIdx.y * 128, col0 = blockIdx.x * 128;

    floatx4 acc[4][4] = {};

    for (int k0 = 0; k0 < K; k0 += 64) {
        #pragma unroll
        for (int i = 0; i < 4; ++i) {
            int u = (wave * 4 + i) * 64 + lane;     // LDS unit this lane fills
            int r = u >> 3, p = u & 7;
            int c = p ^ (r & 7);                    // global 16B-chunk to fetch
            GLDS16(A  + (size_t)(row0 + r) * K + (k0 + c * 8), &sA[(wave * 4 + i) * 512]);
            GLDS16(BT + (size_t)(col0 + r) * K + (k0 + c * 8), &sB[(wave * 4 + i) * 512]);
        }
        asm volatile("s_waitcnt vmcnt(0)" ::: "memory");
        __syncthreads();
        #pragma unroll
        for (int kk = 0; kk < 64; kk += 32) {
            bf16x8 af[4], bfr[4];
            #pragma unroll
            for (int mt = 0; mt < 4; ++mt) {
                int r = wm * 64 + mt * 16 + (lane & 15);
                int c = (kk >> 3) + (lane >> 4);
                af[mt] = *(const bf16x8*)&sA[(r * 8 + (c ^ (r & 7))) * 8];
            }
            #pragma unroll
            for (int nt = 0; nt < 4; ++nt) {
                int r = wn * 64 + nt * 16 + (lane & 15);
                int c = (kk >> 3) + (lane >> 4);
                bfr[nt] = *(const bf16x8*)&sB[(r * 8 + (c ^ (r & 7))) * 8];
            }
            #pragma unroll
            for (int mt = 0; mt < 4; ++mt)
                #pragma unroll
                for (int nt = 0; nt < 4; ++nt)
                    acc[mt][nt] = __builtin_amdgcn_mfma_f32_16x16x32_bf16(
                        af[mt], bfr[nt], acc[mt][nt], 0, 0, 0);
        }
        __syncthreads();
    }
    // epilogue: C/D layout col=lane&15, row=(lane>>4)*4+reg
    #pragma unroll
    for (int mt = 0; mt < 4; ++mt)
        #pragma unroll
        for (int nt = 0; nt < 4; ++nt) {
            int col = col0 + wn * 64 + nt * 16 + (lane & 15);
            #pragma unroll
            for (int i = 0; i < 4; ++i) {
                int row = row0 + wm * 64 + mt * 16 + (lane >> 4) * 4 + i;
                float v = acc[mt][nt][i];
                if (OUT_BF16) ((bf16*)Cv)[(size_t)row * N + col] = (bf16)v;
                else          ((float*)Cv)[(size_t)row * N + col] = v;
            }
        }
}

// ------------------------------------------- fused agg (adj@h) + GraphNorm +
// leaky + readout mean (+ optionally write next-layer scaled input).
// One block per graph; 128-channel chunks; wave w owns channels [w*32,w*32+32).
template<int C, bool WRITE_XS>
__global__ __launch_bounds__(256) void k_agg_gn(
    const bf16* __restrict__ hpre,     // [N_NODES, C]
    const bf16* __restrict__ adjb,     // [N_GRAPHS,64,64], rows pre-scaled by 1/sqrt(deg_in)
    const float* __restrict__ so,      // rsqrt(deg_out), for next-layer scaling
    const float* __restrict__ alpha, const float* __restrict__ gamma,
    const float* __restrict__ beta,
    bf16* __restrict__ xs_out,         // [N_NODES, C] if WRITE_XS
    bf16* __restrict__ Rb, int rbase)
{
    constexpr int CHUNKS = C / 128;
    __shared__ __align__(16) bf16 sAdj[64 * 72];   // row pitch 72 -> 2-way max
    __shared__ __align__(16) bf16 sHT[128 * 72];   // transposed h chunk [ch][s]
    __shared__ float sSc[64];
    int g = blockIdx.x, tid = threadIdx.x;
    int lane = tid & 63, wave = tid >> 6;

    {
        const bf16* ag = adjb + ((size_t)g << 12);
        for (int i = tid; i < 4096; i += 256)
            sAdj[(i >> 6) * 72 + (i & 63)] = ag[i];
        if (tid < 64) sSc[tid] = so[g * 64 + tid];
    }

    for (int cc = 0; cc < CHUNKS; ++cc) {
        __syncthreads();
        for (int i = tid; i < 8192; i += 256) {     // [64 s][128 ch] -> sHT[ch][s]
            int s = i >> 7, ch = i & 127;
            sHT[ch * 72 + s] = hpre[(size_t)(g * 64 + s) * C + cc * 128 + ch];
        }
        __syncthreads();

        floatx4 acc[4][2] = {};
        #pragma unroll
        for (int kk = 0; kk < 64; kk += 32) {
            bf16x8 af[4], bfr[2];
            #pragma unroll
            for (int mt = 0; mt < 4; ++mt)
                af[mt] = *(const bf16x8*)&sAdj[(mt * 16 + (lane & 15)) * 72 + kk + (lane >> 4) * 8];
            #pragma unroll
            for (int nt = 0; nt < 2; ++nt)
                bfr[nt] = *(const bf16x8*)&sHT[((wave * 2 + nt) * 16 + (lane & 15)) * 72 + kk + (lane >> 4) * 8];
            #pragma unroll
            for (int mt = 0; mt < 4; ++mt)
                #pragma unroll
                for (int nt = 0; nt < 2; ++nt)
                    acc[mt][nt] = __builtin_amdgcn_mfma_f32_16x16x32_bf16(
                        af[mt], bfr[nt], acc[mt][nt], 0, 0, 0);
        }

        #pragma unroll
        for (int nt = 0; nt < 2; ++nt) {
            int chg = cc * 128 + (wave * 2 + nt) * 16 + (lane & 15);
            // per-channel sum over 64 nodes: local (4 mt * 4 reg) + xor-shuffle
            float lsum = 0.f;
            #pragma unroll
            for (int mt = 0; mt < 4; ++mt)
                #pragma unroll
                for (int i = 0; i < 4; ++i) lsum += acc[mt][nt][i];
            lsum += __shfl_xor(lsum, 16);
            lsum += __shfl_xor(lsum, 32);
            float mean = lsum * (1.f / 64.f);
            float al = alpha[chg], gm = gamma[chg], bt = beta[chg];
            float am = al * mean;
            float sub[4][4], q = 0.f;
            #pragma unroll
            for (int mt = 0; mt < 4; ++mt)
                #pragma unroll
                for (int i = 0; i < 4; ++i) {
                    float d = acc[mt][nt][i] - am;
                    sub[mt][i] = d; q += d * d;
                }
            q += __shfl_xor(q, 16);
            q += __shfl_xor(q, 32);
            float rs = rsqrtf(q * (1.f / 64.f) + EPS_F);
            float rsum = 0.f;
            #pragma unroll
            for (int mt = 0; mt < 4; ++mt)
                #pragma unroll
                for (int i = 0; i < 4; ++i) {
                    float o = gm * sub[mt][i] * rs + bt;
                    o = (o >= 0.f) ? o : SLOPE_F * o;
                    rsum += o;
                    if (WRITE_XS) {
                        int d = mt * 16 + (lane >> 4) * 4 + i;
                        xs_out[(size_t)(g * 64 + d) * C + chg] = (bf16)(o * sSc[d]);
                    }
                }
            rsum += __shfl_xor(rsum, 16);
            rsum += __shfl_xor(rsum, 32);
            if (lane < 16)
                Rb[(size_t)g * RDIM + rbase + chg] = (bf16)(rsum * (1.f / 64.f));
        }
    }
}

// ------------------------------------------------------- InstanceNorm + leaky
__global__ __launch_bounds__(256) void k_instnorm(
    const float* __restrict__ emb, float* __restrict__ out)
{
    int row = blockIdx.x, tid = threadIdx.x;
    int lane = tid & 63, wave = tid >> 6;
    __shared__ float sS[4], sQ[4];
    float v0 = emb[(size_t)row * EMB_DIM + tid];
    float v1 = emb[(size_t)row * EMB_DIM + 256 + tid];
    float s = v0 + v1, q = v0 * v0 + v1 * v1;
    #pragma unroll
    for (int off = 32; off; off >>= 1) {
        s += __shfl_down(s, off);
        q += __shfl_down(q, off);
    }
    if (lane == 0) { sS[wave] = s; sQ[wave] = q; }
    __syncthreads();
    float S = sS[0] + sS[1] + sS[2] + sS[3];
    float Q = sQ[0] + sQ[1] + sQ[2] + sQ[3];
    float mu = S * (1.f / 512.f);
    float var = Q * (1.f / 512.f) - mu * mu;
    float rs = rsqrtf(var + EPS_F);
    float o0 = (v0 - mu) * rs; o0 = (o0 >= 0.f) ? o0 : SLOPE_F * o0;
    float o1 = (v1 - mu) * rs; o1 = (o1 >= 0.f) ? o1 : SLOPE_F * o1;
    out[(size_t)row * EMB_DIM + tid]       = o0;
    out[(size_t)row * EMB_DIM + 256 + tid] = o1;
}

// ----------------------------------------------------------------- launcher
extern "C" void kernel_launch(void* const* d_in, const int* in_sizes, int n_in,
                              void* d_out, int out_size, void* d_ws, size_t ws_size,
                              hipStream_t stream) {
    const float* x    = (const float*)d_in[0];
    const float* ew   = (const float*)d_in[1];
    const float* W1   = (const float*)d_in[2];
    const float* W2   = (const float*)d_in[3];
    const float* Wemb = (const float*)d_in[4];
    const float* a1   = (const float*)d_in[5];
    const float* g1   = (const float*)d_in[6];
    const float* b1   = (const float*)d_in[7];
    const float* a2   = (const float*)d_in[8];
    const float* g2   = (const float*)d_in[9];
    const float* b2   = (const float*)d_in[10];
    const int* esrc   = (const int*)d_in[11];
    const int* edst   = (const int*)d_in[12];
    float* out = (float*)d_out;

    char* ws = (char*)d_ws;
    const size_t MB = 1024ull * 1024ull;
    bf16*  adjb   = (bf16*)(ws);                       // [0,8M)
    float* scl_o  = (float*)(ws + 8 * MB);             // 256K
    float* scl_i  = (float*)(ws + 8 * MB + 256 * 1024);
    float* deg_o  = (float*)(ws + 8 * MB + 512 * 1024);
    float* deg_i  = (float*)(ws + 8 * MB + 768 * 1024);
    bf16*  Rb     = (bf16*)(ws + 9 * MB);              // 3.5 MB
    bf16*  W1T    = (bf16*)(ws + 13 * MB);             // 1 MB
    bf16*  W2T    = (bf16*)(ws + 14 * MB);             // 0.5 MB
    bf16*  WembT  = (bf16*)(ws + 15 * MB);             // 1.75 MB
    float* emb    = (float*)(ws + 17 * MB);            // 2 MB
    bf16*  xs1    = (bf16*)(ws + 20 * MB);             // 64 MB (dead after GEMM1)
    bf16*  h1pre  = (bf16*)(ws + 84 * MB);             // 128 MB
    bf16*  xs2    = (bf16*)(ws + 212 * MB);            // 128 MB (ends 340M)
    bf16*  h2pre  = (bf16*)(ws + 20 * MB);             // alias xs1 (32 MB)
    float* adjf   = (float*)(ws + 212 * MB);           // alias xs2 (16 MB, dead early)

    hipMemsetAsync(adjf, 0, 16 * MB, stream);
    hipMemsetAsync(deg_o, 0, 512 * 1024, stream);      // deg_o + deg_i contiguous

    k_edges<<<N_EDGES / 256, 256, 0, stream>>>(esrc, edst, ew, adjf, deg_o, deg_i);
    k_scales<<<N_NODES / 256, 256, 0, stream>>>(deg_o, deg_i, scl_o, scl_i);
    k_adjconv<<<(N_GRAPHS * 4096) / 256, 256, 0, stream>>>(adjf, scl_i, adjb);
    k_prep<<<N_GRAPHS, 256, 0, stream>>>(x, scl_o, xs1, Rb);
    k_transpose<<<2048, 256, 0, stream>>>(W1, W1T, 512, 10);
    k_transpose<<<1024, 256, 0, stream>>>(W2, W2T, 1024, 8);
    k_transpose<<<3584, 256, 0, stream>>>(Wemb, WembT, 1792, 9);

    k_gemm<true><<<dim3(HIDDEN / 128, N_NODES / 128), 256, 0, stream>>>(xs1, W1T, h1pre, IN_FEATS, HIDDEN);
    k_agg_gn<HIDDEN, true><<<N_GRAPHS, 256, 0, stream>>>(h1pre, adjb, scl_o, a1, g1, b1, xs2, Rb, 512);
    k_gemm<true><<<dim3(H4 / 128, N_NODES / 128), 256, 0, stream>>>(xs2, W2T, h2pre, HIDDEN, H4);
    k_agg_gn<H4, false><<<N_GRAPHS, 256, 0, stream>>>(h2pre, adjb, scl_o, a2, g2, b2, (bf16*)nullptr, Rb, 1536);
    k_gemm<false><<<dim3(EMB_DIM / 128, N_GRAPHS / 128), 256, 0, stream>>>(Rb, WembT, emb, RDIM, EMB_DIM);
    k_instnorm<<<N_GRAPHS, 256, 0, stream>>>(emb, out);

    (void)in_sizes; (void)n_in; (void)out_size; (void)ws_size;
}

// Round 2
// 646.531 us; speedup vs baseline: 1.0318x; 1.0318x over previous
//
#include <hip/hip_runtime.h>
#include <hip/hip_bf16.h>
#include <stdint.h>

#define N_NODES   65536
#define N_GRAPHS  1024
#define N_EDGES   1048576
#define IN_FEATS  512
#define HIDDEN    1024
#define H4        256
#define EMB_DIM   512
#define RDIM      1792   // 512 + 1024 + 256
#define EPS_F     1e-5f
#define SLOPE_F   0.01f

typedef __bf16 bf16;
typedef __bf16 bf16x4 __attribute__((ext_vector_type(4)));
typedef __bf16 bf16x8 __attribute__((ext_vector_type(8)));
typedef float  floatx4 __attribute__((ext_vector_type(4)));

#define GLDS16(gp, lp) __builtin_amdgcn_global_load_lds( \
    (const __attribute__((address_space(1))) void*)(gp), \
    (__attribute__((address_space(3))) void*)(lp), 16, 0, 0)

// ---------------------------------------------------------------- edge pass
__global__ __launch_bounds__(256) void k_edges(
    const int* __restrict__ src, const int* __restrict__ dst,
    const float* __restrict__ ew,
    float* __restrict__ adj, float* __restrict__ deg_o, float* __restrict__ deg_i)
{
    int e = blockIdx.x * 256 + threadIdx.x;
    int s = src[e], d = dst[e];
    float w = ew[e];
    int g = s >> 6;
    atomicAdd(&adj[((size_t)g << 12) + ((size_t)(d & 63) << 6) + (s & 63)], w);
    atomicAdd(&deg_o[s], 1.0f);
    atomicAdd(&deg_i[d], 1.0f);
}

__global__ __launch_bounds__(256) void k_scales(
    const float* __restrict__ deg_o, const float* __restrict__ deg_i,
    float* __restrict__ so, float* __restrict__ si)
{
    int n = blockIdx.x * 256 + threadIdx.x;
    so[n] = rsqrtf(fmaxf(deg_o[n], 1.0f));
    si[n] = rsqrtf(fmaxf(deg_i[n], 1.0f));
}

// adjb[g][d][s] = bf16( adj * rsqrt(deg_in[g*64+d]) )
__global__ __launch_bounds__(256) void k_adjconv(
    const float* __restrict__ adj, const float* __restrict__ si,
    bf16* __restrict__ adjb)
{
    int idx = blockIdx.x * 256 + threadIdx.x;
    int node = idx >> 6;
    adjb[idx] = (bf16)(adj[idx] * si[node]);
}

// W[K][N] -> WT[N][K] bf16
__global__ __launch_bounds__(256) void k_transpose(
    const float* __restrict__ W, bf16* __restrict__ WT, int K, int logN)
{
    int idx = blockIdx.x * 256 + threadIdx.x;
    if (idx >= (K << logN)) return;
    int n = idx & ((1 << logN) - 1);
    int k = idx >> logN;
    WT[(size_t)n * K + k] = (bf16)W[idx];
}

// ------------------------------------------------ fused prep + agg layer 1
// Per graph: r0 = mean(x); axs1 = adjb @ (x * rsqrt(deg_out)).  Zero LDS:
// B fragments built from direct global x loads (lane=ch -> 4x64B segments).
__global__ __launch_bounds__(256) void k_prep_agg1(
    const float* __restrict__ x, const float* __restrict__ so,
    const bf16* __restrict__ adjb,
    bf16* __restrict__ axs1, bf16* __restrict__ Rb)
{
    int g = blockIdx.x, tid = threadIdx.x;
    int lane = tid & 63, wave = tid >> 6;
    int q = lane >> 4;
    const float* xg = x + (size_t)g * 64 * IN_FEATS;
    const bf16* ag = adjb + ((size_t)g << 12);

    float sov[2][8];
    #pragma unroll
    for (int kk = 0; kk < 2; ++kk)
        #pragma unroll
        for (int j = 0; j < 8; ++j) sov[kk][j] = so[g * 64 + kk * 32 + q * 8 + j];

    bf16x8 af[4][2];
    #pragma unroll
    for (int mt = 0; mt < 4; ++mt)
        #pragma unroll
        for (int kk = 0; kk < 2; ++kk)
            af[mt][kk] = *(const bf16x8*)&ag[(mt * 16 + (lane & 15)) * 64 + kk * 32 + q * 8];

    #pragma unroll
    for (int nt = 0; nt < 8; ++nt) {
        int ch = wave * 128 + nt * 16 + (lane & 15);
        floatx4 acc[4] = {};
        float r0sum = 0.f;
        #pragma unroll
        for (int kk = 0; kk < 2; ++kk) {
            bf16x8 bfrag;
            #pragma unroll
            for (int j = 0; j < 8; ++j) {
                float v = xg[(size_t)(kk * 32 + q * 8 + j) * IN_FEATS + ch];
                r0sum += v;
                bfrag[j] = (bf16)(v * sov[kk][j]);
            }
            #pragma unroll
            for (int mt = 0; mt < 4; ++mt)
                acc[mt] = __builtin_amdgcn_mfma_f32_16x16x32_bf16(af[mt][kk], bfrag, acc[mt], 0, 0, 0);
        }
        r0sum += __shfl_xor(r0sum, 16);
        r0sum += __shfl_xor(r0sum, 32);
        if (lane < 16) Rb[(size_t)g * RDIM + ch] = (bf16)(r0sum * (1.f / 64.f));
        #pragma unroll
        for (int mt = 0; mt < 4; ++mt)
            #pragma unroll
            for (int i = 0; i < 4; ++i) {
                int d = mt * 16 + q * 4 + i;
                axs1[(size_t)(g * 64 + d) * IN_FEATS + ch] = (bf16)acc[mt][i];
            }
    }
}

// --------------------------------------------------- fused MFMA GEMM family
// MODE 0: C = A@BT^T -> float Cout (for readout GEMM)
// MODE 1: GraphNorm + leaky + per-graph mean -> Rb only (layer 2)
// MODE 2: MODE1 + xs=o*so staged to LDS + agg2 = adjb@xs -> axs_out (layer 1)
// 128x128 tile, BK=64, 4 waves (2x2). M-tile = 2 graphs; wave wm owns graph
// by*2+wm entirely -> GraphNorm stats via shfl_xor(16/32).
template<int MODE>
__global__ __launch_bounds__(256) void k_gemm_f(
    const bf16* __restrict__ A, const bf16* __restrict__ BT, int K, int N,
    float* __restrict__ Cout,
    const float* __restrict__ alpha, const float* __restrict__ gamma,
    const float* __restrict__ beta,
    bf16* __restrict__ Rb, int rbase,
    const float* __restrict__ so, const bf16* __restrict__ adjb,
    bf16* __restrict__ axs_out)
{
    constexpr int SMEM = (MODE == 2) ? 18432 : 16384;
    __shared__ __align__(16) bf16 sm[SMEM];
    __shared__ float sSo[128];
    bf16* sA = sm;
    bf16* sB = sm + 8192;

    const int tid = threadIdx.x;
    const int lane = tid & 63, wave = tid >> 6;
    const int q = lane >> 4;
    const int wm = wave & 1, wn = wave >> 1;

    // XCD-aware swizzle: b&7 -> XCD; the CB same-A-tile blocks run
    // back-to-back on one XCD so the A-tile is fetched once per L2.
    int b = blockIdx.y * gridDim.x + blockIdx.x;
    int cb = gridDim.x;
    int xcd = b & 7, t = b >> 3;
    int bx = t % cb;
    int by = (t / cb) * 8 + xcd;
    const int row0 = by * 128, col0 = bx * 128;

    if (MODE == 2 && tid < 128) sSo[tid] = so[by * 128 + tid];

    floatx4 acc[4][4] = {};

    for (int k0 = 0; k0 < K; k0 += 64) {
        #pragma unroll
        for (int i = 0; i < 4; ++i) {
            int u = (wave * 4 + i) * 64 + lane;
            int r = u >> 3, p = u & 7;
            int c = p ^ (r & 7);
            GLDS16(A  + (size_t)(row0 + r) * K + (k0 + c * 8), &sA[(wave * 4 + i) * 512]);
            GLDS16(BT + (size_t)(col0 + r) * K + (k0 + c * 8), &sB[(wave * 4 + i) * 512]);
        }
        asm volatile("s_waitcnt vmcnt(0)" ::: "memory");
        __syncthreads();
        #pragma unroll
        for (int kk = 0; kk < 64; kk += 32) {
            bf16x8 afr[4], bfr[4];
            #pragma unroll
            for (int mt = 0; mt < 4; ++mt) {
                int r = wm * 64 + mt * 16 + (lane & 15);
                int c = (kk >> 3) + q;
                afr[mt] = *(const bf16x8*)&sA[(r * 8 + (c ^ (r & 7))) * 8];
            }
            #pragma unroll
            for (int nt = 0; nt < 4; ++nt) {
                int r = wn * 64 + nt * 16 + (lane & 15);
                int c = (kk >> 3) + q;
                bfr[nt] = *(const bf16x8*)&sB[(r * 8 + (c ^ (r & 7))) * 8];
            }
            #pragma unroll
            for (int mt = 0; mt < 4; ++mt)
                #pragma unroll
                for (int nt = 0; nt < 4; ++nt)
                    acc[mt][nt] = __builtin_amdgcn_mfma_f32_16x16x32_bf16(
                        afr[mt], bfr[nt], acc[mt][nt], 0, 0, 0);
        }
        __syncthreads();
    }

    if (MODE == 0) {
        #pragma unroll
        for (int mt = 0; mt < 4; ++mt)
            #pragma unroll
            for (int nt = 0; nt < 4; ++nt) {
                int col = col0 + wn * 64 + nt * 16 + (lane & 15);
                #pragma unroll
                for (int i = 0; i < 4; ++i) {
                    int row = row0 + wm * 64 + mt * 16 + q * 4 + i;
                    Cout[(size_t)row * N + col] = acc[mt][nt][i];
                }
            }
        return;
    }

    // ---- GraphNorm epilogue (MODE 1/2). Wave wm owns graph gw completely.
    const int gw = by * 2 + wm;
    bf16* xsT = sm + wave * 4608;        // per-wave [64 ch][72] region (MODE 2)

    #pragma unroll
    for (int nt = 0; nt < 4; ++nt) {
        int cl = nt * 16 + (lane & 15);               // col within wave slice
        int colg = col0 + wn * 64 + cl;               // global channel
        float lsum = 0.f;
        #pragma unroll
        for (int mt = 0; mt < 4; ++mt)
            #pragma unroll
            for (int i = 0; i < 4; ++i) lsum += acc[mt][nt][i];
        lsum += __shfl_xor(lsum, 16);
        lsum += __shfl_xor(lsum, 32);
        float mean = lsum * (1.f / 64.f);
        float am = alpha[colg] * mean;
        float gm = gamma[colg], bt = beta[colg];
        float sub[4][4], qv = 0.f;
        #pragma unroll
        for (int mt = 0; mt < 4; ++mt)
            #pragma unroll
            for (int i = 0; i < 4; ++i) {
                float d = acc[mt][nt][i] - am;
                sub[mt][i] = d; qv += d * d;
            }
        qv += __shfl_xor(qv, 16);
        qv += __shfl_xor(qv, 32);
        float rs = rsqrtf(qv * (1.f / 64.f) + EPS_F);
        float rsum = 0.f;
        #pragma unroll
        for (int mt = 0; mt < 4; ++mt) {
            bf16x4 pk;
            #pragma unroll
            for (int i = 0; i < 4; ++i) {
                float o = gm * sub[mt][i] * rs + bt;
                o = (o >= 0.f) ? o : SLOPE_F * o;
                rsum += o;
                if (MODE == 2) pk[i] = (bf16)(o * sSo[wm * 64 + mt * 16 + q * 4 + i]);
            }
            if (MODE == 2)
                *(bf16x4*)&xsT[cl * 72 + mt * 16 + q * 4] = pk;
        }
        rsum += __shfl_xor(rsum, 16);
        rsum += __shfl_xor(rsum, 32);
        if (lane < 16)
            Rb[(size_t)gw * RDIM + rbase + colg] = (bf16)(rsum * (1.f / 64.f));
    }

    if (MODE == 2) {
        asm volatile("s_waitcnt lgkmcnt(0)" ::: "memory");   // wave-local LDS RAW
        const bf16* ag = adjb + ((size_t)gw << 12);
        bf16x8 af2[4][2];
        #pragma unroll
        for (int mt = 0; mt < 4; ++mt)
            #pragma unroll
            for (int kk = 0; kk < 2; ++kk)
                af2[mt][kk] = *(const bf16x8*)&ag[(mt * 16 + (lane & 15)) * 64 + kk * 32 + q * 8];
        #pragma unroll
        for (int nt = 0; nt < 4; ++nt) {
            int cl = nt * 16 + (lane & 15);
            int colg = col0 + wn * 64 + cl;
            floatx4 a2[4] = {};
            #pragma unroll
            for (int kk = 0; kk < 2; ++kk) {
                bf16x8 bfrag = *(const bf16x8*)&xsT[cl * 72 + kk * 32 + q * 8];
                #pragma unroll
                for (int mt = 0; mt < 4; ++mt)
                    a2[mt] = __builtin_amdgcn_mfma_f32_16x16x32_bf16(af2[mt][kk], bfrag, a2[mt], 0, 0, 0);
            }
            #pragma unroll
            for (int mt = 0; mt < 4; ++mt)
                #pragma unroll
                for (int i = 0; i < 4; ++i) {
                    int d = mt * 16 + q * 4 + i;
                    axs_out[(size_t)(gw * 64 + d) * N + colg] = (bf16)a2[mt][i];
                }
        }
    }
}

// ------------------------------------------------------- InstanceNorm + leaky
__global__ __launch_bounds__(256) void k_instnorm(
    const float* __restrict__ emb, float* __restrict__ out)
{
    int row = blockIdx.x, tid = threadIdx.x;
    int lane = tid & 63, wave = tid >> 6;
    __shared__ float sS[4], sQ[4];
    float v0 = emb[(size_t)row * EMB_DIM + tid];
    float v1 = emb[(size_t)row * EMB_DIM + 256 + tid];
    float s = v0 + v1, q = v0 * v0 + v1 * v1;
    #pragma unroll
    for (int off = 32; off; off >>= 1) {
        s += __shfl_down(s, off);
        q += __shfl_down(q, off);
    }
    if (lane == 0) { sS[wave] = s; sQ[wave] = q; }
    __syncthreads();
    float S = sS[0] + sS[1] + sS[2] + sS[3];
    float Q = sQ[0] + sQ[1] + sQ[2] + sQ[3];
    float mu = S * (1.f / 512.f);
    float var = Q * (1.f / 512.f) - mu * mu;
    float rs = rsqrtf(var + EPS_F);
    float o0 = (v0 - mu) * rs; o0 = (o0 >= 0.f) ? o0 : SLOPE_F * o0;
    float o1 = (v1 - mu) * rs; o1 = (o1 >= 0.f) ? o1 : SLOPE_F * o1;
    out[(size_t)row * EMB_DIM + tid]       = o0;
    out[(size_t)row * EMB_DIM + 256 + tid] = o1;
}

// ----------------------------------------------------------------- launcher
extern "C" void kernel_launch(void* const* d_in, const int* in_sizes, int n_in,
                              void* d_out, int out_size, void* d_ws, size_t ws_size,
                              hipStream_t stream) {
    const float* x    = (const float*)d_in[0];
    const float* ew   = (const float*)d_in[1];
    const float* W1   = (const float*)d_in[2];
    const float* W2   = (const float*)d_in[3];
    const float* Wemb = (const float*)d_in[4];
    const float* a1   = (const float*)d_in[5];
    const float* g1   = (const float*)d_in[6];
    const float* b1   = (const float*)d_in[7];
    const float* a2   = (const float*)d_in[8];
    const float* g2   = (const float*)d_in[9];
    const float* b2   = (const float*)d_in[10];
    const int* esrc   = (const int*)d_in[11];
    const int* edst   = (const int*)d_in[12];
    float* out = (float*)d_out;

    char* ws = (char*)d_ws;
    const size_t MB = 1024ull * 1024ull;
    bf16*  adjb   = (bf16*)(ws);                       // 8 MB
    float* scl_o  = (float*)(ws + 8 * MB);
    float* scl_i  = (float*)(ws + 8 * MB + 256 * 1024);
    float* deg_o  = (float*)(ws + 8 * MB + 512 * 1024);
    float* deg_i  = (float*)(ws + 8 * MB + 768 * 1024);
    bf16*  Rb     = (bf16*)(ws + 9 * MB);              // 3.5 MB
    bf16*  W1T    = (bf16*)(ws + 13 * MB);             // 1 MB
    bf16*  W2T    = (bf16*)(ws + 14 * MB);             // 0.5 MB
    bf16*  WembT  = (bf16*)(ws + 15 * MB);             // 1.75 MB
    float* emb    = (float*)(ws + 17 * MB);            // 2 MB
    bf16*  axs1   = (bf16*)(ws + 20 * MB);             // 64 MB
    bf16*  axs2   = (bf16*)(ws + 84 * MB);             // 128 MB (ends 212M)
    float* adjf   = (float*)(ws + 212 * MB);           // 16 MB

    hipMemsetAsync(adjf, 0, 16 * MB, stream);
    hipMemsetAsync(deg_o, 0, 512 * 1024, stream);

    k_edges<<<N_EDGES / 256, 256, 0, stream>>>(esrc, edst, ew, adjf, deg_o, deg_i);
    k_scales<<<N_NODES / 256, 256, 0, stream>>>(deg_o, deg_i, scl_o, scl_i);
    k_adjconv<<<(N_GRAPHS * 4096) / 256, 256, 0, stream>>>(adjf, scl_i, adjb);
    k_transpose<<<2048, 256, 0, stream>>>(W1, W1T, 512, 10);
    k_transpose<<<1024, 256, 0, stream>>>(W2, W2T, 1024, 8);
    k_transpose<<<3584, 256, 0, stream>>>(Wemb, WembT, 1792, 9);

    k_prep_agg1<<<N_GRAPHS, 256, 0, stream>>>(x, scl_o, adjb, axs1, Rb);

    // layer 1: (axs1 @ W1) -> GN -> leaky -> r1 -> xs -> adj@xs -> axs2
    k_gemm_f<2><<<dim3(HIDDEN / 128, N_NODES / 128), 256, 0, stream>>>(
        axs1, W1T, IN_FEATS, HIDDEN, nullptr, a1, g1, b1, Rb, 512, scl_o, adjb, axs2);
    // layer 2: (axs2 @ W2) -> GN -> leaky -> r2 (nothing else materialized)
    k_gemm_f<1><<<dim3(H4 / 128, N_NODES / 128), 256, 0, stream>>>(
        axs2, W2T, HIDDEN, H4, nullptr, a2, g2, b2, Rb, 1536, nullptr, nullptr, nullptr);
    // readout GEMM
    k_gemm_f<0><<<dim3(EMB_DIM / 128, N_GRAPHS / 128), 256, 0, stream>>>(
        Rb, WembT, RDIM, EMB_DIM, emb, nullptr, nullptr, nullptr, nullptr, 0, nullptr, nullptr, nullptr);
    k_instnorm<<<N_GRAPHS, 256, 0, stream>>>(emb, out);

    (void)in_sizes; (void)n_in; (void)out_size; (void)ws_size;
}

// Round 3
// 490.710 us; speedup vs baseline: 1.3594x; 1.3175x over previous
//
#include <hip/hip_runtime.h>
#include <hip/hip_bf16.h>
#include <stdint.h>

#define N_NODES   65536
#define N_GRAPHS  1024
#define N_EDGES   1048576
#define IN_FEATS  512
#define HIDDEN    1024
#define H4        256
#define EMB_DIM   512
#define RDIM      1792   // 512 + 1024 + 256
#define EPS_F     1e-5f
#define SLOPE_F   0.01f

typedef __bf16 bf16;
typedef __bf16 bf16x8 __attribute__((ext_vector_type(8)));
typedef float  floatx4 __attribute__((ext_vector_type(4)));

#define GLDS16(gp, lp) __builtin_amdgcn_global_load_lds( \
    (const __attribute__((address_space(1))) void*)(gp), \
    (__attribute__((address_space(3))) void*)(lp), 16, 0, 0)

// -------------------------------------------- fused edge pass, per graph
// edges e in [g*1024,(g+1)*1024) all belong to graph g (by construction).
__global__ __launch_bounds__(256) void k_graph_build(
    const int* __restrict__ src, const int* __restrict__ dst,
    const float* __restrict__ ew,
    bf16* __restrict__ adjb, float* __restrict__ scl_o)
{
    __shared__ float sAdj[4096];
    __shared__ float sDegO[64], sDegI[64];
    int g = blockIdx.x, tid = threadIdx.x;
    for (int i = tid; i < 4096; i += 256) sAdj[i] = 0.f;
    if (tid < 64) { sDegO[tid] = 0.f; sDegI[tid] = 0.f; }
    __syncthreads();
    int e0 = g * 1024;
    #pragma unroll
    for (int i = 0; i < 4; ++i) {
        int e = e0 + i * 256 + tid;
        int s = src[e] & 63, d = dst[e] & 63;
        atomicAdd(&sAdj[(d << 6) | s], ew[e]);
        atomicAdd(&sDegO[s], 1.f);
        atomicAdd(&sDegI[d], 1.f);
    }
    __syncthreads();
    if (tid < 64) scl_o[g * 64 + tid] = rsqrtf(fmaxf(sDegO[tid], 1.f));
    bf16* ag = adjb + ((size_t)g << 12);
    for (int i = tid; i < 4096; i += 256) {
        float si = rsqrtf(fmaxf(sDegI[i >> 6], 1.f));
        ag[i] = (bf16)(sAdj[i] * si);
    }
}

// W[K][N] -> WT[N][K] bf16
__global__ __launch_bounds__(256) void k_transpose(
    const float* __restrict__ W, bf16* __restrict__ WT, int K, int logN)
{
    int idx = blockIdx.x * 256 + threadIdx.x;
    if (idx >= (K << logN)) return;
    int n = idx & ((1 << logN) - 1);
    int k = idx >> logN;
    WT[(size_t)n * K + k] = (bf16)W[idx];
}

// -------------------------------------- fused prep + agg layer 1 (2 blk/graph)
// r0 = mean(x) (256-ch half); axs1 = adjb @ (x * rsqrt(deg_out)), bounced
// through LDS for coalesced bf16x8 stores.
__global__ __launch_bounds__(256) void k_prep_agg1(
    const float* __restrict__ x, const float* __restrict__ so,
    const bf16* __restrict__ adjb,
    bf16* __restrict__ axs1, bf16* __restrict__ Rb)
{
    __shared__ __align__(16) bf16 sOut[64 * 264];
    __shared__ float sSo[64];
    int g = blockIdx.x >> 1, half = blockIdx.x & 1;
    int tid = threadIdx.x, lane = tid & 63, wave = tid >> 6, q = lane >> 4;
    if (tid < 64) sSo[tid] = so[g * 64 + tid];
    const float* xg = x + (size_t)g * 64 * IN_FEATS + half * 256;
    const bf16* ag = adjb + ((size_t)g << 12);

    bf16x8 af[4][2];
    #pragma unroll
    for (int mt = 0; mt < 4; ++mt)
        #pragma unroll
        for (int kk = 0; kk < 2; ++kk)
            af[mt][kk] = *(const bf16x8*)&ag[(mt * 16 + (lane & 15)) * 64 + kk * 32 + q * 8];
    __syncthreads();
    float sov[2][8];
    #pragma unroll
    for (int kk = 0; kk < 2; ++kk)
        #pragma unroll
        for (int j = 0; j < 8; ++j) sov[kk][j] = sSo[kk * 32 + q * 8 + j];

    #pragma unroll
    for (int nt = 0; nt < 4; ++nt) {
        int cl = wave * 64 + nt * 16 + (lane & 15);     // 0..255
        floatx4 acc[4] = {};
        float r0 = 0.f;
        #pragma unroll
        for (int kk = 0; kk < 2; ++kk) {
            bf16x8 bfrag;
            #pragma unroll
            for (int j = 0; j < 8; ++j) {
                float v = xg[(size_t)(kk * 32 + q * 8 + j) * IN_FEATS + cl];
                r0 += v;
                bfrag[j] = (bf16)(v * sov[kk][j]);
            }
            #pragma unroll
            for (int mt = 0; mt < 4; ++mt)
                acc[mt] = __builtin_amdgcn_mfma_f32_16x16x32_bf16(af[mt][kk], bfrag, acc[mt], 0, 0, 0);
        }
        r0 += __shfl_xor(r0, 16);
        r0 += __shfl_xor(r0, 32);
        if (lane < 16) Rb[(size_t)g * RDIM + half * 256 + cl] = (bf16)(r0 * (1.f / 64.f));
        #pragma unroll
        for (int mt = 0; mt < 4; ++mt)
            #pragma unroll
            for (int i = 0; i < 4; ++i)
                sOut[(mt * 16 + q * 4 + i) * 264 + cl] = (bf16)acc[mt][i];
    }
    __syncthreads();
    #pragma unroll
    for (int it = 0; it < 8; ++it) {
        int idx = it * 256 + tid;
        int d = idx >> 5, c8 = idx & 31;
        *(bf16x8*)&axs1[(size_t)(g * 64 + d) * IN_FEATS + half * 256 + c8 * 8] =
            *(const bf16x8*)&sOut[d * 264 + c8 * 8];
    }
}

// ----------------------------------------------------- shared GEMM main loop
// 128x128 tile, BK=64, XOR-swizzled LDS staging via global_load_lds width=16.
__device__ __forceinline__ void gemm_mainloop(
    const bf16* __restrict__ A, const bf16* __restrict__ BT, int K,
    int row0, int col0, int lane, int wave, int wm, int wn, int q,
    bf16* sA, bf16* sB, floatx4 (&acc)[4][4])
{
    for (int k0 = 0; k0 < K; k0 += 64) {
        #pragma unroll
        for (int i = 0; i < 4; ++i) {
            int u = (wave * 4 + i) * 64 + lane;
            int r = u >> 3, p = u & 7;
            int c = p ^ (r & 7);
            GLDS16(A  + (size_t)(row0 + r) * K + (k0 + c * 8), &sA[(wave * 4 + i) * 512]);
            GLDS16(BT + (size_t)(col0 + r) * K + (k0 + c * 8), &sB[(wave * 4 + i) * 512]);
        }
        asm volatile("s_waitcnt vmcnt(0)" ::: "memory");
        __syncthreads();
        #pragma unroll
        for (int kk = 0; kk < 64; kk += 32) {
            bf16x8 afr[4], bfr[4];
            #pragma unroll
            for (int mt = 0; mt < 4; ++mt) {
                int r = wm * 64 + mt * 16 + (lane & 15);
                int c = (kk >> 3) + q;
                afr[mt] = *(const bf16x8*)&sA[(r * 8 + (c ^ (r & 7))) * 8];
            }
            #pragma unroll
            for (int nt = 0; nt < 4; ++nt) {
                int r = wn * 64 + nt * 16 + (lane & 15);
                int c = (kk >> 3) + q;
                bfr[nt] = *(const bf16x8*)&sB[(r * 8 + (c ^ (r & 7))) * 8];
            }
            #pragma unroll
            for (int mt = 0; mt < 4; ++mt)
                #pragma unroll
                for (int nt = 0; nt < 4; ++nt)
                    acc[mt][nt] = __builtin_amdgcn_mfma_f32_16x16x32_bf16(
                        afr[mt], bfr[nt], acc[mt][nt], 0, 0, 0);
        }
        __syncthreads();
    }
}

__device__ __forceinline__ void swizzle_block(int cb, int& bx, int& by)
{
    int b = blockIdx.y * gridDim.x + blockIdx.x;
    int xcd = b & 7, t = b >> 3;
    bx = t % cb;
    by = (t / cb) * 8 + xcd;
}

// ---------------- GEMM1: axs1@W1 + GraphNorm + leaky + r1 + xs2(scaled) store
__global__ __launch_bounds__(256) void k_gemm1_f(
    const bf16* __restrict__ A, const bf16* __restrict__ BT,
    const float* __restrict__ alpha, const float* __restrict__ gamma,
    const float* __restrict__ beta,
    const float* __restrict__ so,
    bf16* __restrict__ xs2, bf16* __restrict__ Rb)
{
    __shared__ __align__(16) bf16 sm[128 * 136];   // >= 16384 staging
    __shared__ float sSo[128];
    bf16* sA = sm;
    bf16* sB = sm + 8192;
    const int tid = threadIdx.x;
    const int lane = tid & 63, wave = tid >> 6, q = lane >> 4;
    const int wm = wave & 1, wn = wave >> 1;
    int bx, by; swizzle_block(gridDim.x, bx, by);
    const int row0 = by * 128, col0 = bx * 128;

    if (tid < 128) sSo[tid] = so[row0 + tid];

    floatx4 acc[4][4] = {};
    gemm_mainloop(A, BT, IN_FEATS, row0, col0, lane, wave, wm, wn, q, sA, sB, acc);

    const int gw = by * 2 + wm;
    bf16* sOut = sm;                                // [128 r][136 pitch]
    #pragma unroll
    for (int nt = 0; nt < 4; ++nt) {
        int cl = wn * 64 + nt * 16 + (lane & 15);
        int colg = col0 + cl;
        float lsum = 0.f;
        #pragma unroll
        for (int mt = 0; mt < 4; ++mt)
            #pragma unroll
            for (int i = 0; i < 4; ++i) lsum += acc[mt][nt][i];
        lsum += __shfl_xor(lsum, 16);
        lsum += __shfl_xor(lsum, 32);
        float am = alpha[colg] * (lsum * (1.f / 64.f));
        float gm = gamma[colg], bt = beta[colg];
        float sub[4][4], qv = 0.f;
        #pragma unroll
        for (int mt = 0; mt < 4; ++mt)
            #pragma unroll
            for (int i = 0; i < 4; ++i) {
                float d = acc[mt][nt][i] - am;
                sub[mt][i] = d; qv += d * d;
            }
        qv += __shfl_xor(qv, 16);
        qv += __shfl_xor(qv, 32);
        float rs = rsqrtf(qv * (1.f / 64.f) + EPS_F);
        float rsum = 0.f;
        #pragma unroll
        for (int mt = 0; mt < 4; ++mt)
            #pragma unroll
            for (int i = 0; i < 4; ++i) {
                float o = gm * sub[mt][i] * rs + bt;
                o = (o >= 0.f) ? o : SLOPE_F * o;
                rsum += o;
                int r = wm * 64 + mt * 16 + q * 4 + i;
                sOut[r * 136 + cl] = (bf16)(o * sSo[r]);
            }
        rsum += __shfl_xor(rsum, 16);
        rsum += __shfl_xor(rsum, 32);
        if (lane < 16)
            Rb[(size_t)gw * RDIM + 512 + colg] = (bf16)(rsum * (1.f / 64.f));
    }
    __syncthreads();
    #pragma unroll
    for (int it = 0; it < 8; ++it) {
        int idx = it * 256 + tid;
        int r = idx >> 4, c8 = idx & 15;
        *(bf16x8*)&xs2[(size_t)(row0 + r) * HIDDEN + col0 + c8 * 8] =
            *(const bf16x8*)&sOut[r * 136 + c8 * 8];
    }
}

// ---- GEMM2: xs2@W2, then IN-LDS transpose + wave-local agg (adj@y) + GN + r2
__global__ __launch_bounds__(256) void k_gemm2_f(
    const bf16* __restrict__ A, const bf16* __restrict__ BT,
    const bf16* __restrict__ adjb,
    const float* __restrict__ alpha, const float* __restrict__ gamma,
    const float* __restrict__ beta,
    bf16* __restrict__ Rb)
{
    __shared__ __align__(16) bf16 sm[128 * 136];
    bf16* sA = sm;
    bf16* sB = sm + 8192;
    const int tid = threadIdx.x;
    const int lane = tid & 63, wave = tid >> 6, q = lane >> 4;
    const int wm = wave & 1, wn = wave >> 1;
    int bx, by; swizzle_block(gridDim.x, bx, by);
    const int row0 = by * 128, col0 = bx * 128;

    floatx4 acc[4][4] = {};
    gemm_mainloop(A, BT, HIDDEN, row0, col0, lane, wave, wm, wn, q, sA, sB, acc);

    // transpose y-tile into LDS [ch 128][node 136-pitch] (wave-local quadrant)
    bf16* sT = sm;
    #pragma unroll
    for (int nt = 0; nt < 4; ++nt) {
        int cl = wn * 64 + nt * 16 + (lane & 15);
        #pragma unroll
        for (int mt = 0; mt < 4; ++mt)
            #pragma unroll
            for (int i = 0; i < 4; ++i)
                sT[cl * 136 + wm * 64 + mt * 16 + q * 4 + i] = (bf16)acc[mt][nt][i];
    }
    asm volatile("s_waitcnt lgkmcnt(0)" ::: "memory");   // wave-local LDS RAW

    // h2 = adj_gw @ y  (64x64 @ 64x64 per wave)
    const int gw = by * 2 + wm;
    const bf16* ag = adjb + ((size_t)gw << 12);
    floatx4 a2[4][4] = {};
    #pragma unroll
    for (int kk = 0; kk < 2; ++kk) {
        bf16x8 afr[4], bfr[4];
        #pragma unroll
        for (int mt = 0; mt < 4; ++mt)
            afr[mt] = *(const bf16x8*)&ag[(mt * 16 + (lane & 15)) * 64 + kk * 32 + q * 8];
        #pragma unroll
        for (int nt = 0; nt < 4; ++nt)
            bfr[nt] = *(const bf16x8*)&sT[(wn * 64 + nt * 16 + (lane & 15)) * 136 + wm * 64 + kk * 32 + q * 8];
        #pragma unroll
        for (int mt = 0; mt < 4; ++mt)
            #pragma unroll
            for (int nt = 0; nt < 4; ++nt)
                a2[mt][nt] = __builtin_amdgcn_mfma_f32_16x16x32_bf16(afr[mt], bfr[nt], a2[mt][nt], 0, 0, 0);
    }

    // GraphNorm + leaky + r2 (no global h2)
    #pragma unroll
    for (int nt = 0; nt < 4; ++nt) {
        int colg = col0 + wn * 64 + nt * 16 + (lane & 15);
        float lsum = 0.f;
        #pragma unroll
        for (int mt = 0; mt < 4; ++mt)
            #pragma unroll
            for (int i = 0; i < 4; ++i) lsum += a2[mt][nt][i];
        lsum += __shfl_xor(lsum, 16);
        lsum += __shfl_xor(lsum, 32);
        float am = alpha[colg] * (lsum * (1.f / 64.f));
        float gm = gamma[colg], bt = beta[colg];
        float sub[4][4], qv = 0.f;
        #pragma unroll
        for (int mt = 0; mt < 4; ++mt)
            #pragma unroll
            for (int i = 0; i < 4; ++i) {
                float d = a2[mt][nt][i] - am;
                sub[mt][i] = d; qv += d * d;
            }
        qv += __shfl_xor(qv, 16);
        qv += __shfl_xor(qv, 32);
        float rs = rsqrtf(qv * (1.f / 64.f) + EPS_F);
        float rsum = 0.f;
        #pragma unroll
        for (int mt = 0; mt < 4; ++mt)
            #pragma unroll
            for (int i = 0; i < 4; ++i) {
                float o = gm * sub[mt][i] * rs + bt;
                rsum += (o >= 0.f) ? o : SLOPE_F * o;
            }
        rsum += __shfl_xor(rsum, 16);
        rsum += __shfl_xor(rsum, 32);
        if (lane < 16)
            Rb[(size_t)gw * RDIM + 1536 + colg] = (bf16)(rsum * (1.f / 64.f));
    }
}

// ----------------------------------------------- readout GEMM (plain, fp32 C)
__global__ __launch_bounds__(256) void k_gemm_ro(
    const bf16* __restrict__ A, const bf16* __restrict__ BT,
    float* __restrict__ Cout)
{
    __shared__ __align__(16) bf16 sm[16384];
    bf16* sA = sm;
    bf16* sB = sm + 8192;
    const int tid = threadIdx.x;
    const int lane = tid & 63, wave = tid >> 6, q = lane >> 4;
    const int wm = wave & 1, wn = wave >> 1;
    int bx, by; swizzle_block(gridDim.x, bx, by);
    const int row0 = by * 128, col0 = bx * 128;

    floatx4 acc[4][4] = {};
    gemm_mainloop(A, BT, RDIM, row0, col0, lane, wave, wm, wn, q, sA, sB, acc);

    #pragma unroll
    for (int mt = 0; mt < 4; ++mt)
        #pragma unroll
        for (int nt = 0; nt < 4; ++nt) {
            int col = col0 + wn * 64 + nt * 16 + (lane & 15);
            #pragma unroll
            for (int i = 0; i < 4; ++i) {
                int row = row0 + wm * 64 + mt * 16 + q * 4 + i;
                Cout[(size_t)row * EMB_DIM + col] = acc[mt][nt][i];
            }
        }
}

// ------------------------------------------------------- InstanceNorm + leaky
__global__ __launch_bounds__(256) void k_instnorm(
    const float* __restrict__ emb, float* __restrict__ out)
{
    int row = blockIdx.x, tid = threadIdx.x;
    int lane = tid & 63, wave = tid >> 6;
    __shared__ float sS[4], sQ[4];
    float v0 = emb[(size_t)row * EMB_DIM + tid];
    float v1 = emb[(size_t)row * EMB_DIM + 256 + tid];
    float s = v0 + v1, q = v0 * v0 + v1 * v1;
    #pragma unroll
    for (int off = 32; off; off >>= 1) {
        s += __shfl_down(s, off);
        q += __shfl_down(q, off);
    }
    if (lane == 0) { sS[wave] = s; sQ[wave] = q; }
    __syncthreads();
    float S = sS[0] + sS[1] + sS[2] + sS[3];
    float Q = sQ[0] + sQ[1] + sQ[2] + sQ[3];
    float mu = S * (1.f / 512.f);
    float var = Q * (1.f / 512.f) - mu * mu;
    float rs = rsqrtf(var + EPS_F);
    float o0 = (v0 - mu) * rs; o0 = (o0 >= 0.f) ? o0 : SLOPE_F * o0;
    float o1 = (v1 - mu) * rs; o1 = (o1 >= 0.f) ? o1 : SLOPE_F * o1;
    out[(size_t)row * EMB_DIM + tid]       = o0;
    out[(size_t)row * EMB_DIM + 256 + tid] = o1;
}

// ----------------------------------------------------------------- launcher
extern "C" void kernel_launch(void* const* d_in, const int* in_sizes, int n_in,
                              void* d_out, int out_size, void* d_ws, size_t ws_size,
                              hipStream_t stream) {
    const float* x    = (const float*)d_in[0];
    const float* ew   = (const float*)d_in[1];
    const float* W1   = (const float*)d_in[2];
    const float* W2   = (const float*)d_in[3];
    const float* Wemb = (const float*)d_in[4];
    const float* a1   = (const float*)d_in[5];
    const float* g1   = (const float*)d_in[6];
    const float* b1   = (const float*)d_in[7];
    const float* a2   = (const float*)d_in[8];
    const float* g2   = (const float*)d_in[9];
    const float* b2   = (const float*)d_in[10];
    const int* esrc   = (const int*)d_in[11];
    const int* edst   = (const int*)d_in[12];
    float* out = (float*)d_out;

    char* ws = (char*)d_ws;
    const size_t MB = 1024ull * 1024ull;
    bf16*  adjb   = (bf16*)(ws);                       // 8 MB
    float* scl_o  = (float*)(ws + 8 * MB);             // 256 KB
    bf16*  Rb     = (bf16*)(ws + 9 * MB);              // 3.5 MB
    bf16*  W1T    = (bf16*)(ws + 13 * MB);             // 1 MB
    bf16*  W2T    = (bf16*)(ws + 14 * MB);             // 0.5 MB
    bf16*  WembT  = (bf16*)(ws + 15 * MB);             // 1.75 MB
    float* emb    = (float*)(ws + 17 * MB);            // 2 MB
    bf16*  axs1   = (bf16*)(ws + 20 * MB);             // 64 MB
    bf16*  xs2    = (bf16*)(ws + 84 * MB);             // 128 MB (ends 212M)

    k_graph_build<<<N_GRAPHS, 256, 0, stream>>>(esrc, edst, ew, adjb, scl_o);
    k_transpose<<<2048, 256, 0, stream>>>(W1, W1T, 512, 10);
    k_transpose<<<1024, 256, 0, stream>>>(W2, W2T, 1024, 8);
    k_transpose<<<3584, 256, 0, stream>>>(Wemb, WembT, 1792, 9);

    k_prep_agg1<<<N_GRAPHS * 2, 256, 0, stream>>>(x, scl_o, adjb, axs1, Rb);

    k_gemm1_f<<<dim3(HIDDEN / 128, N_NODES / 128), 256, 0, stream>>>(
        axs1, W1T, a1, g1, b1, scl_o, xs2, Rb);
    k_gemm2_f<<<dim3(H4 / 128, N_NODES / 128), 256, 0, stream>>>(
        xs2, W2T, adjb, a2, g2, b2, Rb);
    k_gemm_ro<<<dim3(EMB_DIM / 128, N_GRAPHS / 128), 256, 0, stream>>>(
        Rb, WembT, emb);
    k_instnorm<<<N_GRAPHS, 256, 0, stream>>>(emb, out);

    (void)in_sizes; (void)n_in; (void)out_size; (void)ws_size;
}